// Round 1
// baseline (212.298 us; speedup 1.0000x reference)
//
#include <hip/hip_runtime.h>

// YOLOv1 loss: batch x 7 x 7 x 30 fp32 inputs (y_trues, y_preds) -> scalar.
// Memory-bound: one coalesced pass over ~193 MB, roofline ~31 us @ 6.3 TB/s.

#define SS 49      // S*S
#define DD 30      // C + 5*B

__device__ __forceinline__ float iou_yolo(const float b1[4], const float b2[4]) {
    const float EPS = 1e-6f;
    float b1x1 = b1[0] - b1[2] * 0.5f, b1y1 = b1[1] - b1[3] * 0.5f;
    float b1x2 = b1[0] + b1[2] * 0.5f, b1y2 = b1[1] + b1[3] * 0.5f;
    float b2x1 = b2[0] - b2[2] * 0.5f, b2y1 = b2[1] - b2[3] * 0.5f;
    float b2x2 = b2[0] + b2[2] * 0.5f, b2y2 = b2[1] + b2[3] * 0.5f;
    float iw = fmaxf(fminf(b1x2, b2x2) - fmaxf(b1x1, b2x1), 0.0f);
    float ih = fmaxf(fminf(b1y2, b2y2) - fmaxf(b1y1, b2y1), 0.0f);
    float inter = iw * ih;
    float a1 = fabsf((b1x2 - b1x1) * (b1y2 - b1y1));
    float a2 = fabsf((b2x2 - b2x1) * (b2y2 - b2y1));
    return inter / (a1 + a2 - inter + EPS);
}

__global__ __launch_bounds__(256)
void yolo_loss_kernel(const float* __restrict__ yt_g,
                      const float* __restrict__ yp_g,
                      float* __restrict__ out,
                      int ncells, float inv_batch) {
    const float LAMBDA_COORD = 5.0f;
    const float LAMBDA_NOOBJ = 0.5f;
    const float EPS = 1e-6f;

    int cell = blockIdx.x * blockDim.x + threadIdx.x;
    float per_cell = 0.0f;

    if (cell < ncells) {
        // 120-byte row per cell; 8B-aligned -> float2 vector loads.
        const float2* yt2 = reinterpret_cast<const float2*>(yt_g + (size_t)cell * DD);
        const float2* yp2 = reinterpret_cast<const float2*>(yp_g + (size_t)cell * DD);
        float yt[DD], yp[DD];
#pragma unroll
        for (int i = 0; i < DD / 2; ++i) {
            float2 a = yt2[i]; yt[2 * i] = a.x; yt[2 * i + 1] = a.y;
            float2 b = yp2[i]; yp[2 * i] = b.x; yp[2 * i + 1] = b.y;
        }

        float obj = (yt[4] == 1.0f) ? 1.0f : 0.0f;
        float noobj = 1.0f - obj;

        float iou1 = iou_yolo(&yt[0], &yp[0]);
        float iou2 = iou_yolo(&yt[0], &yp[5]);
        bool best1 = iou1 > iou2;

        float bh0 = best1 ? yp[0] : yp[5];
        float bh1 = best1 ? yp[1] : yp[6];
        float bh2 = best1 ? yp[2] : yp[7];
        float bh3 = best1 ? yp[3] : yp[8];
        float conf_hat       = best1 ? yp[4] : yp[9];
        float other_conf_hat = best1 ? yp[9] : yp[4];

        float dx = yt[0] - bh0, dy = yt[1] - bh1;
        float xy = dx * dx + dy * dy;

        float sw = sqrtf(yt[2]) - sqrtf(fabsf(bh2 + EPS));
        float sh = sqrtf(yt[3]) - sqrtf(fabsf(bh3 + EPS));
        float wh = sw * sw + sh * sh;

        float dc = yt[4] - conf_hat;
        float obj_conf = dc * dc;

        float noobj_in_obj = LAMBDA_NOOBJ * other_conf_hat * other_conf_hat;

        float d4 = yt[4] - yp[4];
        float d9 = yt[4] - yp[9];
        float noobj_cells = LAMBDA_NOOBJ * (d4 * d4 + d9 * d9);

        float cls = 0.0f;
#pragma unroll
        for (int k = 10; k < DD; ++k) {
            float d = yt[k] - yp[k];
            cls += d * d;
        }

        per_cell = obj * (LAMBDA_COORD * (xy + wh) + obj_conf + noobj_in_obj + cls)
                 + noobj * noobj_cells;
    }

    // Wave-level reduce (64 lanes), then cross-wave via LDS, one atomic/block.
#pragma unroll
    for (int off = 32; off > 0; off >>= 1)
        per_cell += __shfl_down(per_cell, off, 64);

    __shared__ float smem[4];  // 256 threads / 64 lanes
    int lane = threadIdx.x & 63;
    int wave = threadIdx.x >> 6;
    if (lane == 0) smem[wave] = per_cell;
    __syncthreads();
    if (threadIdx.x == 0) {
        float s = smem[0] + smem[1] + smem[2] + smem[3];
        atomicAdd(out, s * inv_batch);
    }
}

extern "C" void kernel_launch(void* const* d_in, const int* in_sizes, int n_in,
                              void* d_out, int out_size, void* d_ws, size_t ws_size,
                              hipStream_t stream) {
    const float* yt = (const float*)d_in[0];
    const float* yp = (const float*)d_in[1];
    float* out = (float*)d_out;

    int total = in_sizes[0];          // batch * S*S * D
    int ncells = total / DD;          // batch * 49
    int batch = ncells / SS;

    // d_out is re-poisoned (0xAA) before every timed launch.
    hipMemsetAsync(out, 0, sizeof(float), stream);

    int block = 256;
    int grid = (ncells + block - 1) / block;
    yolo_loss_kernel<<<grid, block, 0, stream>>>(yt, yp, out, ncells, 1.0f / (float)batch);
}